// Round 4
// baseline (3124.856 us; speedup 1.0000x reference)
//
#include <hip/hip_runtime.h>
#include <cmath>
#include <cstddef>

#define F_IN 128
#define H_DIM 64
#define C_OUT 40
#define MAXDEG 5
#define EPB 16
#define BN 256          // nodes per bucket
#define ASTRIDE 68      // padded LDS stride (floats): banks (dl*4+lane)%32 -> 2-way, free

typedef __attribute__((ext_vector_type(8))) short short8;
typedef __attribute__((ext_vector_type(4))) float fv4;

__device__ __forceinline__ float b2f(unsigned short u) {
    unsigned x = ((unsigned)u) << 16;
    return __builtin_bit_cast(float, x);
}
__device__ __forceinline__ unsigned short f2b(float f) {
    unsigned u = __builtin_bit_cast(unsigned, f);
    u = (u + 0x7FFF + ((u >> 16) & 1)) >> 16;
    return (unsigned short)u;
}

// ============ bucket-grouping build (256-node buckets) ============
// bucket b = dst >> 8; packed edge = (dst&255)<<18 | src   (src < 2^18)

__global__ void k_hist(const int* __restrict__ src, const int* __restrict__ dst,
                       int E, int NB, int* __restrict__ bkt_cnt) {
    __shared__ int h[1024];
    for (int i = threadIdx.x; i < NB; i += blockDim.x) h[i] = 0;
    __syncthreads();
    int stride = gridDim.x * blockDim.x;
    for (int e = blockIdx.x * blockDim.x + threadIdx.x; e < E; e += stride) {
        int s = src[e], d = dst[e];
        if (s != d) atomicAdd(&h[d >> 8], 1);
    }
    __syncthreads();
    for (int i = threadIdx.x; i < NB; i += blockDim.x)
        if (h[i]) atomicAdd(&bkt_cnt[i], h[i]);
}

__global__ void k_bktscan(const int* __restrict__ bkt_cnt, int NB,
                          int* __restrict__ bkt_off, int* __restrict__ gcur) {
    __shared__ int sh[1024];
    int tid = threadIdx.x;
    int v = (tid < NB) ? bkt_cnt[tid] : 0;
    sh[tid] = v;
    __syncthreads();
    for (int off = 1; off < 1024; off <<= 1) {
        int t = (tid >= off) ? sh[tid - off] : 0;
        __syncthreads();
        sh[tid] += t;
        __syncthreads();
    }
    if (tid < NB) {
        int ex = sh[tid] - v;
        bkt_off[tid] = ex;
        gcur[tid] = ex;
    }
    if (tid == 1023) bkt_off[NB] = sh[1023];
}

__global__ __launch_bounds__(256) void k_scatter(const int* __restrict__ src,
                                                 const int* __restrict__ dst,
                                                 int E, int NB, int* __restrict__ gcur,
                                                 unsigned int* __restrict__ ebuf) {
    __shared__ int hist[1024];
    __shared__ int base[1024];
    for (int i = threadIdx.x; i < NB; i += 256) hist[i] = 0;
    __syncthreads();
    int e0 = blockIdx.x * (256 * EPB);
    int es[EPB], ed[EPB];
#pragma unroll
    for (int i = 0; i < EPB; ++i) {
        int e = e0 + i * 256 + threadIdx.x;
        int s = -1, d = -1;
        if (e < E) { s = src[e]; d = dst[e]; }
        es[i] = s; ed[i] = d;
        if (d >= 0 && s != d) atomicAdd(&hist[d >> 8], 1);
    }
    __syncthreads();
    for (int i = threadIdx.x; i < NB; i += 256) {
        int c = hist[i];
        base[i] = c ? atomicAdd(&gcur[i], c) : 0;
    }
    __syncthreads();
    for (int i = threadIdx.x; i < NB; i += 256) hist[i] = 0;
    __syncthreads();
#pragma unroll
    for (int i = 0; i < EPB; ++i) {
        int s = es[i], d = ed[i];
        if (d >= 0 && s != d) {
            int b = d >> 8;
            int p = atomicAdd(&hist[b], 1);
            ebuf[base[b] + p] = ((unsigned)(d & 255) << 18) | (unsigned)s;
        }
    }
}

// ---------------- h0 = relu(x @ W1 + b1), MFMA bf16 ----------------
__global__ __launch_bounds__(256) void k_lin1(const float* __restrict__ x,
                                              const float* __restrict__ W1,
                                              const float* __restrict__ b1,
                                              unsigned short* __restrict__ h, int N) {
    __shared__ unsigned short Wl[4 * 4 * 64 * 8];
    int tid = threadIdx.x;
    for (int idx = tid; idx < 4 * 4 * 64 * 8; idx += 256) {
        int j = idx & 7, ln = (idx >> 3) & 63, ks = (idx >> 9) & 3, t = idx >> 11;
        int k = ks * 32 + (ln >> 4) * 8 + j;
        int n = t * 16 + (ln & 15);
        Wl[idx] = f2b(W1[k * H_DIM + n]);
    }
    __syncthreads();

    int wave = tid >> 6, lane = tid & 63;
    int tile = blockIdx.x * 4 + wave;
    int row0 = tile * 16;
    if (row0 >= N) return;
    int m = lane & 15, quad = lane >> 4;
    int row = row0 + m;
    if (row >= N) row = N - 1;

    short8 a[4];
    const float* xr = x + (size_t)row * F_IN + quad * 8;
#pragma unroll
    for (int ks = 0; ks < 4; ++ks) {
        fv4 lo = *(const fv4*)(xr + ks * 32);
        fv4 hi = *(const fv4*)(xr + ks * 32 + 4);
        short8 av;
#pragma unroll
        for (int j = 0; j < 4; ++j) av[j] = (short)f2b(lo[j]);
#pragma unroll
        for (int j = 0; j < 4; ++j) av[4 + j] = (short)f2b(hi[j]);
        a[ks] = av;
    }

    fv4 acc[4];
#pragma unroll
    for (int t = 0; t < 4; ++t) acc[t] = (fv4){0.f, 0.f, 0.f, 0.f};
#pragma unroll
    for (int ks = 0; ks < 4; ++ks) {
#pragma unroll
        for (int t = 0; t < 4; ++t) {
            short8 b = *(const short8*)&Wl[(((t * 4 + ks) * 64) + lane) * 8];
            acc[t] = __builtin_amdgcn_mfma_f32_16x16x32_bf16(a[ks], b, acc[t], 0, 0, 0);
        }
    }
#pragma unroll
    for (int t = 0; t < 4; ++t) {
        int n = t * 16 + m;
        float bias = b1[n];
#pragma unroll
        for (int reg = 0; reg < 4; ++reg) {
            int r = row0 + quad * 4 + reg;
            if (r < N) {
                float v = acc[t][reg] + bias;
                h[(size_t)r * H_DIM + n] = f2b(fmaxf(v, 0.f));
            }
        }
    }
}

// ---------------- fused: aggregate (LDS) + bucket GEMM + residual + fixup ----------------
__global__ __launch_bounds__(1024, 4) void k_fused(
    const unsigned short* __restrict__ hin,
    const unsigned int* __restrict__ ebuf,
    const int* __restrict__ bkt_off,
    const float* __restrict__ relW, const float* __restrict__ relb,
    const float* __restrict__ fuse, int layer,
    const unsigned short* __restrict__ xfirst,
    unsigned short* __restrict__ hout, int N)
{
    __shared__ float acc[BN * ASTRIDE];            // 69632 B
    __shared__ unsigned short Wl[4 * 2 * 64 * 8];  // 8192 B
    __shared__ int icnt[BN];                       // 1024 B
    __shared__ int fixlist[128];
    __shared__ int fixn;

    int tid = threadIdx.x;
    int bk = blockIdx.x;
    int n0 = bk * BN;

    // stage W5 as B-fragments
    const float* W = relW + (size_t)(layer * 6 + MAXDEG) * (H_DIM * H_DIM);
    for (int idx = tid; idx < 4 * 2 * 64 * 8; idx += 1024) {
        int j = idx & 7, ln = (idx >> 3) & 63, ks = (idx >> 9) & 1, t = idx >> 10;
        int k = ks * 32 + (ln >> 4) * 8 + j;
        int n = t * 16 + (ln & 15);
        Wl[idx] = f2b(W[k * H_DIM + n]);
    }
    for (int i = tid; i < BN; i += 1024) icnt[i] = 0;
    if (tid == 0) fixn = 0;

    // init acc with self term (16 consecutive elems per thread, within one row)
    {
        int i0 = tid * 16;               // 1024*16 = BN*64
        int dl = i0 >> 6, f0 = i0 & 63;
        int n = n0 + dl;
        float* dp = &acc[dl * ASTRIDE + f0];
        if (n < N) {
            const unsigned short* sp = hin + (size_t)n * H_DIM + f0;
#pragma unroll
            for (int k = 0; k < 16; ++k) dp[k] = b2f(sp[k]);
        } else {
#pragma unroll
            for (int k = 0; k < 16; ++k) dp[k] = 0.f;
        }
    }
    __syncthreads();

    // edge phase: wave handles 64-edge chunks; ds_add_f32 fire-and-forget
    int ebase = bkt_off[bk], eend = bkt_off[bk + 1];
    int wid = tid >> 6, lane = tid & 63;
    for (int ch = ebase + wid * 64; ch < eend; ch += 16 * 64) {
        int e = ch + lane;
        int pk = 0;
        if (e < eend) {
            pk = (int)ebuf[e];
            atomicAdd(&icnt[((unsigned)pk) >> 18], 1);
        }
        int m = min(64, eend - ch);
        int j = 0;
        for (; j + 16 <= m; j += 16) {
            unsigned pp[16];
#pragma unroll
            for (int i = 0; i < 16; ++i) pp[i] = (unsigned)__shfl(pk, j + i);
            float vv[16];
#pragma unroll
            for (int i = 0; i < 16; ++i)
                vv[i] = b2f(hin[(size_t)(pp[i] & 0x3FFFF) * H_DIM + lane]);
#pragma unroll
            for (int i = 0; i < 16; ++i)
                atomicAdd(&acc[(pp[i] >> 18) * ASTRIDE + lane], vv[i]);
        }
        for (; j < m; ++j) {
            unsigned p = (unsigned)__shfl(pk, j);
            float v = b2f(hin[(size_t)(p & 0x3FFFF) * H_DIM + lane]);
            atomicAdd(&acc[(p >> 18) * ASTRIDE + lane], v);
        }
    }
    __syncthreads();

    // rare deg<5 rows -> fixlist
    if (tid < BN) {
        int n = n0 + tid;
        if (n < N && icnt[tid] < MAXDEG) {
            int p = atomicAdd(&fixn, 1);
            if (p < 128) fixlist[p] = tid;
        }
    }
    __syncthreads();

    float fu = fuse[layer];
    const float* bias = relb + (layer * 6 + MAXDEG) * H_DIM;

    // GEMM phase: wave wid -> rows [wid*16, wid*16+16)
    {
        int ml = lane & 15, quad = lane >> 4;
        int rl0 = wid * 16;
        short8 a[2];
#pragma unroll
        for (int ks = 0; ks < 2; ++ks) {
            const float* ap = &acc[(rl0 + ml) * ASTRIDE + ks * 32 + quad * 8];
            short8 av;
#pragma unroll
            for (int j = 0; j < 8; ++j) av[j] = (short)f2b(ap[j]);
            a[ks] = av;
        }
        fv4 cacc[4];
#pragma unroll
        for (int t = 0; t < 4; ++t) cacc[t] = (fv4){0.f, 0.f, 0.f, 0.f};
#pragma unroll
        for (int ks = 0; ks < 2; ++ks)
#pragma unroll
            for (int t = 0; t < 4; ++t) {
                short8 b = *(const short8*)&Wl[(((t * 2 + ks) * 64) + lane) * 8];
                cacc[t] = __builtin_amdgcn_mfma_f32_16x16x32_bf16(a[ks], b, cacc[t], 0, 0, 0);
            }
#pragma unroll
        for (int t = 0; t < 4; ++t) {
            int n = t * 16 + ml;
            float bv = bias[n];
#pragma unroll
            for (int reg = 0; reg < 4; ++reg) {
                int rl = rl0 + quad * 4 + reg;
                int r = n0 + rl;
                if (r < N && icnt[rl] >= MAXDEG) {
                    float v = cacc[t][reg] + bv + fu * b2f(xfirst[(size_t)r * H_DIM + n]);
                    hout[(size_t)r * H_DIM + n] = f2b(v);
                }
            }
        }
    }

    // fixup rows (deg<5), one wave each, f32 matvec
    int M = min(fixn, 128);
    for (int i = wid; i < M; i += 16) {
        int rl = fixlist[i];
        int r = n0 + rl;
        int d = icnt[rl];
        const float* Wd = relW + (size_t)(layer * 6 + d) * (H_DIM * H_DIM);
        float av = relb[(layer * 6 + d) * H_DIM + lane];
        for (int k = 0; k < 64; ++k)
            av = fmaf(acc[rl * ASTRIDE + k], Wd[k * H_DIM + lane], av);
        av += fu * b2f(xfirst[(size_t)r * H_DIM + lane]);
        hout[(size_t)r * H_DIM + lane] = f2b(av);
    }
}

// ---------------- logits + log_softmax via MFMA ----------------
__global__ __launch_bounds__(256) void k_out(const unsigned short* __restrict__ h,
                                             const float* __restrict__ Wout,
                                             const float* __restrict__ bout,
                                             float* __restrict__ out, int N) {
    __shared__ unsigned short Wl[3 * 2 * 64 * 8];
    int tid = threadIdx.x;
    for (int idx = tid; idx < 3 * 2 * 64 * 8; idx += 256) {
        int j = idx & 7, ln = (idx >> 3) & 63, ks = (idx >> 9) & 1, t = idx >> 10;
        int k = ks * 32 + (ln >> 4) * 8 + j;
        int n = t * 16 + (ln & 15);
        Wl[idx] = (n < C_OUT) ? f2b(Wout[k * C_OUT + n]) : 0;
    }
    __syncthreads();

    int wave = tid >> 6, lane = tid & 63;
    int tile = blockIdx.x * 4 + wave;
    int row0 = tile * 16;
    if (row0 >= N) return;
    int m = lane & 15, quad = lane >> 4;
    int row = row0 + m;
    if (row >= N) row = N - 1;

    short8 a[2];
#pragma unroll
    for (int ks = 0; ks < 2; ++ks)
        a[ks] = *(const short8*)(h + (size_t)row * H_DIM + ks * 32 + quad * 8);

    fv4 acc[3];
#pragma unroll
    for (int t = 0; t < 3; ++t) acc[t] = (fv4){0.f, 0.f, 0.f, 0.f};
#pragma unroll
    for (int ks = 0; ks < 2; ++ks) {
#pragma unroll
        for (int t = 0; t < 3; ++t) {
            short8 b = *(const short8*)&Wl[(((t * 2 + ks) * 64) + lane) * 8];
            acc[t] = __builtin_amdgcn_mfma_f32_16x16x32_bf16(a[ks], b, acc[t], 0, 0, 0);
        }
    }
    bool v2 = (m < 8);
    float b0 = bout[m], b1v = bout[16 + m], b2v = v2 ? bout[32 + m] : 0.f;
#pragma unroll
    for (int reg = 0; reg < 4; ++reg) {
        int r = row0 + quad * 4 + reg;
        float l0 = acc[0][reg] + b0;
        float l1 = acc[1][reg] + b1v;
        float l2 = v2 ? (acc[2][reg] + b2v) : -INFINITY;
        float mx = fmaxf(fmaxf(l0, l1), l2);
#pragma unroll
        for (int off = 1; off < 16; off <<= 1) mx = fmaxf(mx, __shfl_xor(mx, off));
        float s = expf(l0 - mx) + expf(l1 - mx) + (v2 ? expf(l2 - mx) : 0.f);
#pragma unroll
        for (int off = 1; off < 16; off <<= 1) s += __shfl_xor(s, off);
        float ls = logf(s);
        if (r < N) {
            out[(size_t)r * C_OUT + m] = l0 - mx - ls;
            out[(size_t)r * C_OUT + 16 + m] = l1 - mx - ls;
            if (v2) out[(size_t)r * C_OUT + 32 + m] = l2 - mx - ls;
        }
    }
}

extern "C" void kernel_launch(void* const* d_in, const int* in_sizes, int n_in,
                              void* d_out, int out_size, void* d_ws, size_t ws_size,
                              hipStream_t stream) {
    const float* x    = (const float*)d_in[0];
    const int*   ei   = (const int*)d_in[1];
    const float* W1   = (const float*)d_in[2];
    const float* b1   = (const float*)d_in[3];
    const float* relW = (const float*)d_in[4];
    const float* relb = (const float*)d_in[5];
    const float* Wout = (const float*)d_in[6];
    const float* bout = (const float*)d_in[7];
    const float* fuse = (const float*)d_in[8];
    float* out = (float*)d_out;

    int N = in_sizes[0] / F_IN;
    int E = in_sizes[1] / 2;
    const int* src = ei;
    const int* dst = ei + E;
    int NB = (N + BN - 1) / BN;   // 782 for N=200000; needs src < 2^18

    char* w = (char*)d_ws;
    auto alloc = [&](size_t bytes) {
        char* p = w;
        w += (bytes + 255) & ~(size_t)255;
        return p;
    };
    int* bkt_cnt = (int*)alloc(1056 * 4);
    int* bkt_off = (int*)alloc(1056 * 4);
    int* gcur    = (int*)alloc(1056 * 4);
    unsigned int* ebuf = (unsigned int*)alloc((size_t)E * 4);
    unsigned short* h0 = (unsigned short*)alloc((size_t)N * H_DIM * 2);
    unsigned short* h1 = (unsigned short*)alloc((size_t)N * H_DIM * 2);
    unsigned short* h2 = (unsigned short*)alloc((size_t)N * H_DIM * 2);

    hipMemsetAsync(bkt_cnt, 0, 1056 * 4, stream);

    k_hist<<<512, 256, 0, stream>>>(src, dst, E, NB, bkt_cnt);
    k_bktscan<<<1, 1024, 0, stream>>>(bkt_cnt, NB, bkt_off, gcur);
    k_scatter<<<(E + 256 * EPB - 1) / (256 * EPB), 256, 0, stream>>>(src, dst, E, NB, gcur, ebuf);

    int tiles = (N + 15) / 16;
    int gblk = (tiles + 3) / 4;

    k_lin1<<<gblk, 256, 0, stream>>>(x, W1, b1, h0, N);

    k_fused<<<NB, 1024, 0, stream>>>(h0, ebuf, bkt_off, relW, relb, fuse, 0, h0, h1, N);
    k_fused<<<NB, 1024, 0, stream>>>(h1, ebuf, bkt_off, relW, relb, fuse, 1, h0, h2, N);

    k_out<<<gblk, 256, 0, stream>>>(h2, Wout, bout, out, N);
}

// Round 5
// 550.800 us; speedup vs baseline: 5.6733x; 5.6733x over previous
//
#include <hip/hip_runtime.h>
#include <cmath>
#include <cstddef>

#define F_IN 128
#define H_DIM 64
#define C_OUT 40
#define MAXDEG 5
#define EPB 16

typedef __attribute__((ext_vector_type(8))) short short8;
typedef __attribute__((ext_vector_type(4))) float fv4;

__device__ __forceinline__ float b2f(unsigned short u) {
    unsigned x = ((unsigned)u) << 16;
    return __builtin_bit_cast(float, x);
}
__device__ __forceinline__ unsigned short f2b(float f) {
    unsigned u = __builtin_bit_cast(unsigned, f);
    u = (u + 0x7FFF + ((u >> 16) & 1)) >> 16;
    return (unsigned short)u;
}

// ============ CSR build: fixed-stride 1024-node buckets (no hist/scan passes) ============
// bucket b = dst >> 10; packed edge = (dst&1023)<<20 | src  (needs src < 2^20)

__global__ __launch_bounds__(256) void k_scatter(const int* __restrict__ src,
                                                 const int* __restrict__ dst,
                                                 int E, int NB, int stride,
                                                 int* __restrict__ gcnt,
                                                 unsigned int* __restrict__ ebuf) {
    __shared__ int hist[256];
    __shared__ int base[256];
    int tid = threadIdx.x;
    if (tid < NB) hist[tid] = 0;
    __syncthreads();
    int e0 = blockIdx.x * (256 * EPB);
    int es[EPB], ed[EPB];
#pragma unroll
    for (int i = 0; i < EPB; ++i) {
        int e = e0 + i * 256 + tid;
        int s = -1, d = -1;
        if (e < E) { s = src[e]; d = dst[e]; }
        es[i] = s; ed[i] = d;
        if (d >= 0 && s != d) atomicAdd(&hist[d >> 10], 1);
    }
    __syncthreads();
    if (tid < NB) {
        int c = hist[tid];
        base[tid] = c ? atomicAdd(&gcnt[tid], c) : 0;
        hist[tid] = 0;
    }
    __syncthreads();
#pragma unroll
    for (int i = 0; i < EPB; ++i) {
        int s = es[i], d = ed[i];
        if (d >= 0 && s != d) {
            int b = d >> 10;
            int p = base[b] + atomicAdd(&hist[b], 1);
            if (p < stride)  // overflow guard (slack is ~20 sigma; never hit for random data)
                ebuf[(size_t)b * stride + p] = ((unsigned)(d & 1023) << 20) | (unsigned)s;
        }
    }
}

// per-bucket counting sort into col (positions share ebuf's strided index space)
__global__ __launch_bounds__(1024) void k_build(const unsigned int* __restrict__ ebuf,
                                                const int* __restrict__ gcnt, int stride, int N,
                                                int* __restrict__ row, int* __restrict__ cnt,
                                                int* __restrict__ col, int* __restrict__ list,
                                                int* __restrict__ listctr) {
    __shared__ int lcnt[1024];
    __shared__ int lcur[1024];
    int bk = blockIdx.x;
    int n0 = bk << 10;
    int tid = threadIdx.x;
    int ebase = bk * stride;
    int ec = min(gcnt[bk], stride);
    int eend = ebase + ec;
    lcnt[tid] = 0;
    __syncthreads();
    for (int e = ebase + tid; e < eend; e += 1024)
        atomicAdd(&lcnt[ebuf[e] >> 20], 1);
    __syncthreads();
    int v = lcnt[tid];
    lcur[tid] = v;
    __syncthreads();
    for (int off = 1; off < 1024; off <<= 1) {
        int t = (tid >= off) ? lcur[tid - off] : 0;
        __syncthreads();
        lcur[tid] += t;
        __syncthreads();
    }
    int ex = lcur[tid] - v;
    __syncthreads();
    lcur[tid] = ebase + ex;
    int n = n0 + tid;
    if (n < N) {
        row[n] = ebase + ex;
        cnt[n] = v;
        if (v < MAXDEG) {
            int p = atomicAdd(listctr, 1);
            list[p] = n;
        }
    }
    __syncthreads();
    for (int e = ebase + tid; e < eend; e += 1024) {
        unsigned edv = ebuf[e];
        int dl = edv >> 20;
        int p = atomicAdd(&lcur[dl], 1);
        col[p] = (int)(edv & 0xFFFFF);
    }
}

// ---------------- h0 = relu(x @ W1 + b1), MFMA bf16 ----------------
__global__ __launch_bounds__(256) void k_lin1(const float* __restrict__ x,
                                              const float* __restrict__ W1,
                                              const float* __restrict__ b1,
                                              unsigned short* __restrict__ h, int N) {
    __shared__ unsigned short Wl[4 * 4 * 64 * 8];
    int tid = threadIdx.x;
    for (int idx = tid; idx < 4 * 4 * 64 * 8; idx += 256) {
        int j = idx & 7, ln = (idx >> 3) & 63, ks = (idx >> 9) & 3, t = idx >> 11;
        int k = ks * 32 + (ln >> 4) * 8 + j;
        int n = t * 16 + (ln & 15);
        Wl[idx] = f2b(W1[k * H_DIM + n]);
    }
    __syncthreads();

    int wave = tid >> 6, lane = tid & 63;
    int tile = blockIdx.x * 4 + wave;
    int row0 = tile * 16;
    if (row0 >= N) return;
    int m = lane & 15, quad = lane >> 4;
    int row = row0 + m;
    if (row >= N) row = N - 1;

    short8 a[4];
    const float* xr = x + (size_t)row * F_IN + quad * 8;
#pragma unroll
    for (int ks = 0; ks < 4; ++ks) {
        fv4 lo = *(const fv4*)(xr + ks * 32);
        fv4 hi = *(const fv4*)(xr + ks * 32 + 4);
        short8 av;
#pragma unroll
        for (int j = 0; j < 4; ++j) av[j] = (short)f2b(lo[j]);
#pragma unroll
        for (int j = 0; j < 4; ++j) av[4 + j] = (short)f2b(hi[j]);
        a[ks] = av;
    }

    fv4 acc[4];
#pragma unroll
    for (int t = 0; t < 4; ++t) acc[t] = (fv4){0.f, 0.f, 0.f, 0.f};
#pragma unroll
    for (int ks = 0; ks < 4; ++ks) {
#pragma unroll
        for (int t = 0; t < 4; ++t) {
            short8 b = *(const short8*)&Wl[(((t * 4 + ks) * 64) + lane) * 8];
            acc[t] = __builtin_amdgcn_mfma_f32_16x16x32_bf16(a[ks], b, acc[t], 0, 0, 0);
        }
    }
#pragma unroll
    for (int t = 0; t < 4; ++t) {
        int n = t * 16 + m;
        float bias = b1[n];
#pragma unroll
        for (int reg = 0; reg < 4; ++reg) {
            int r = row0 + quad * 4 + reg;
            if (r < N) {
                float v = acc[t][reg] + bias;
                h[(size_t)r * H_DIM + n] = f2b(fmaxf(v, 0.f));
            }
        }
    }
}

// ---------------- agg[n] = h[n] + sum h[src], u32-vectorized (2 feat/lane, 2 edges/wave) ----
__global__ void k_agg(const unsigned short* __restrict__ hin, const int* __restrict__ row,
                      const int* __restrict__ cnt, const int* __restrict__ col,
                      unsigned short* __restrict__ agg, int N) {
    int gid = blockIdx.x * blockDim.x + threadIdx.x;
    int n = gid >> 6, lane = gid & 63;
    if (n >= N) return;
    int g = lane >> 5;          // edge subgroup (0/1)
    int f = lane & 31;          // feature pair: features [2f, 2f+1]
    int base = row[n];
    int c = cnt[n];
    const unsigned* hw = (const unsigned*)hin;   // u32 view, row stride 32
    float a0 = 0.f, a1 = 0.f;
    for (int j0 = 0; j0 < c; j0 += 64) {
        int idx = j0 + lane;
        int myc = (idx < c) ? col[base + idx] : 0;
        int mm = min(64, c - j0);
        int t = 0;
        for (; t + 8 <= mm; t += 8) {   // 8 edges, 4 u32 loads/lane in flight
            unsigned s0 = (unsigned)__shfl(myc, t + g);
            unsigned s1 = (unsigned)__shfl(myc, t + 2 + g);
            unsigned s2 = (unsigned)__shfl(myc, t + 4 + g);
            unsigned s3 = (unsigned)__shfl(myc, t + 6 + g);
            unsigned u0 = hw[(size_t)s0 * 32 + f];
            unsigned u1 = hw[(size_t)s1 * 32 + f];
            unsigned u2 = hw[(size_t)s2 * 32 + f];
            unsigned u3 = hw[(size_t)s3 * 32 + f];
            a0 += __builtin_bit_cast(float, u0 << 16);
            a1 += __builtin_bit_cast(float, u0 & 0xFFFF0000u);
            a0 += __builtin_bit_cast(float, u1 << 16);
            a1 += __builtin_bit_cast(float, u1 & 0xFFFF0000u);
            a0 += __builtin_bit_cast(float, u2 << 16);
            a1 += __builtin_bit_cast(float, u2 & 0xFFFF0000u);
            a0 += __builtin_bit_cast(float, u3 << 16);
            a1 += __builtin_bit_cast(float, u3 & 0xFFFF0000u);
        }
        for (; t < mm; t += 2) {
            int e = t + g;
            if (e < mm) {
                unsigned s = (unsigned)__shfl(myc, e);
                unsigned u = hw[(size_t)s * 32 + f];
                a0 += __builtin_bit_cast(float, u << 16);
                a1 += __builtin_bit_cast(float, u & 0xFFFF0000u);
            }
        }
    }
    // combine the two edge-subgroups
    a0 += __shfl_xor(a0, 32);
    a1 += __shfl_xor(a1, 32);
    // self term
    unsigned us = hw[(size_t)n * 32 + f];
    a0 += __builtin_bit_cast(float, us << 16);
    a1 += __builtin_bit_cast(float, us & 0xFFFF0000u);
    if (g == 0) {
        unsigned lo = (unsigned)f2b(a0);
        unsigned hi = (unsigned)f2b(a1);
        ((unsigned*)agg)[(size_t)n * 32 + f] = lo | (hi << 16);
    }
}

// ---------------- bucket-5 GEMM for ALL nodes ----------------
__global__ __launch_bounds__(256) void k_bucket(const unsigned short* __restrict__ agg,
                                                const float* __restrict__ relW,
                                                const float* __restrict__ relb,
                                                const float* __restrict__ fuse, int layer,
                                                const unsigned short* __restrict__ xfirst,
                                                unsigned short* __restrict__ h, int N) {
    __shared__ unsigned short Wl[4 * 2 * 64 * 8];
    const float* W = relW + (size_t)(layer * 6 + MAXDEG) * (H_DIM * H_DIM);
    int tid = threadIdx.x;
    for (int idx = tid; idx < 4 * 2 * 64 * 8; idx += 256) {
        int j = idx & 7, ln = (idx >> 3) & 63, ks = (idx >> 9) & 1, t = idx >> 10;
        int k = ks * 32 + (ln >> 4) * 8 + j;
        int n = t * 16 + (ln & 15);
        Wl[idx] = f2b(W[k * H_DIM + n]);
    }
    __syncthreads();

    int wave = tid >> 6, lane = tid & 63;
    int tile = blockIdx.x * 4 + wave;
    int row0 = tile * 16;
    if (row0 >= N) return;
    int m = lane & 15, quad = lane >> 4;
    int row = row0 + m;
    if (row >= N) row = N - 1;

    short8 a[2];
#pragma unroll
    for (int ks = 0; ks < 2; ++ks)
        a[ks] = *(const short8*)(agg + (size_t)row * H_DIM + ks * 32 + quad * 8);

    fv4 acc[4];
#pragma unroll
    for (int t = 0; t < 4; ++t) acc[t] = (fv4){0.f, 0.f, 0.f, 0.f};
#pragma unroll
    for (int ks = 0; ks < 2; ++ks) {
#pragma unroll
        for (int t = 0; t < 4; ++t) {
            short8 b = *(const short8*)&Wl[(((t * 2 + ks) * 64) + lane) * 8];
            acc[t] = __builtin_amdgcn_mfma_f32_16x16x32_bf16(a[ks], b, acc[t], 0, 0, 0);
        }
    }
    float fu = fuse[layer];
    const float* bias = relb + (layer * 6 + MAXDEG) * H_DIM;
#pragma unroll
    for (int t = 0; t < 4; ++t) {
        int n = t * 16 + m;
        float bv = bias[n];
#pragma unroll
        for (int reg = 0; reg < 4; ++reg) {
            int r = row0 + quad * 4 + reg;
            if (r < N) {
                float v = acc[t][reg] + bv + fu * b2f(xfirst[(size_t)r * H_DIM + n]);
                h[(size_t)r * H_DIM + n] = f2b(v);
            }
        }
    }
}

// ---------------- fixup for rare deg<5 nodes ----------------
__global__ void k_fixup(const unsigned short* __restrict__ agg, const int* __restrict__ list,
                        const int* __restrict__ listctr, const int* __restrict__ cnt,
                        const float* __restrict__ relW, const float* __restrict__ relb,
                        const float* __restrict__ fuse, int layer,
                        const unsigned short* __restrict__ xfirst,
                        unsigned short* __restrict__ h) {
    int gid = blockIdx.x * blockDim.x + threadIdx.x;
    int wave = gid >> 6, lane = gid & 63;
    int nwaves = (gridDim.x * blockDim.x) >> 6;
    int M = *listctr;
    float fu = fuse[layer];
    for (int i = wave; i < M; i += nwaves) {
        int n = list[i];
        int d = cnt[n];
        const float* W = relW + (size_t)(layer * 6 + d) * (H_DIM * H_DIM);
        float a = b2f(agg[(size_t)n * H_DIM + lane]);
        float acc = relb[(layer * 6 + d) * H_DIM + lane];
#pragma unroll 16
        for (int k = 0; k < 64; ++k)
            acc = fmaf(__shfl(a, k), W[k * H_DIM + lane], acc);
        acc += fu * b2f(xfirst[(size_t)n * H_DIM + lane]);
        h[(size_t)n * H_DIM + lane] = f2b(acc);
    }
}

// ---------------- logits + log_softmax via MFMA ----------------
__global__ __launch_bounds__(256) void k_out(const unsigned short* __restrict__ h,
                                             const float* __restrict__ Wout,
                                             const float* __restrict__ bout,
                                             float* __restrict__ out, int N) {
    __shared__ unsigned short Wl[3 * 2 * 64 * 8];
    int tid = threadIdx.x;
    for (int idx = tid; idx < 3 * 2 * 64 * 8; idx += 256) {
        int j = idx & 7, ln = (idx >> 3) & 63, ks = (idx >> 9) & 1, t = idx >> 10;
        int k = ks * 32 + (ln >> 4) * 8 + j;
        int n = t * 16 + (ln & 15);
        Wl[idx] = (n < C_OUT) ? f2b(Wout[k * C_OUT + n]) : 0;
    }
    __syncthreads();

    int wave = tid >> 6, lane = tid & 63;
    int tile = blockIdx.x * 4 + wave;
    int row0 = tile * 16;
    if (row0 >= N) return;
    int m = lane & 15, quad = lane >> 4;
    int row = row0 + m;
    if (row >= N) row = N - 1;

    short8 a[2];
#pragma unroll
    for (int ks = 0; ks < 2; ++ks)
        a[ks] = *(const short8*)(h + (size_t)row * H_DIM + ks * 32 + quad * 8);

    fv4 acc[3];
#pragma unroll
    for (int t = 0; t < 3; ++t) acc[t] = (fv4){0.f, 0.f, 0.f, 0.f};
#pragma unroll
    for (int ks = 0; ks < 2; ++ks) {
#pragma unroll
        for (int t = 0; t < 3; ++t) {
            short8 b = *(const short8*)&Wl[(((t * 2 + ks) * 64) + lane) * 8];
            acc[t] = __builtin_amdgcn_mfma_f32_16x16x32_bf16(a[ks], b, acc[t], 0, 0, 0);
        }
    }
    bool v2 = (m < 8);
    float b0 = bout[m], b1v = bout[16 + m], b2v = v2 ? bout[32 + m] : 0.f;
#pragma unroll
    for (int reg = 0; reg < 4; ++reg) {
        int r = row0 + quad * 4 + reg;
        float l0 = acc[0][reg] + b0;
        float l1 = acc[1][reg] + b1v;
        float l2 = v2 ? (acc[2][reg] + b2v) : -INFINITY;
        float mx = fmaxf(fmaxf(l0, l1), l2);
#pragma unroll
        for (int off = 1; off < 16; off <<= 1) mx = fmaxf(mx, __shfl_xor(mx, off));
        float s = expf(l0 - mx) + expf(l1 - mx) + (v2 ? expf(l2 - mx) : 0.f);
#pragma unroll
        for (int off = 1; off < 16; off <<= 1) s += __shfl_xor(s, off);
        float ls = logf(s);
        if (r < N) {
            out[(size_t)r * C_OUT + m] = l0 - mx - ls;
            out[(size_t)r * C_OUT + 16 + m] = l1 - mx - ls;
            if (v2) out[(size_t)r * C_OUT + 32 + m] = l2 - mx - ls;
        }
    }
}

extern "C" void kernel_launch(void* const* d_in, const int* in_sizes, int n_in,
                              void* d_out, int out_size, void* d_ws, size_t ws_size,
                              hipStream_t stream) {
    const float* x    = (const float*)d_in[0];
    const int*   ei   = (const int*)d_in[1];
    const float* W1   = (const float*)d_in[2];
    const float* b1   = (const float*)d_in[3];
    const float* relW = (const float*)d_in[4];
    const float* relb = (const float*)d_in[5];
    const float* Wout = (const float*)d_in[6];
    const float* bout = (const float*)d_in[7];
    const float* fuse = (const float*)d_in[8];
    float* out = (float*)d_out;

    int N = in_sizes[0] / F_IN;
    int E = in_sizes[1] / 2;
    const int* src = ei;
    const int* dst = ei + E;
    int NB = (N + 1023) >> 10;             // 196 buckets (needs N <= 262144)
    int mean = (E + NB - 1) / NB;          // ~16.3k edges per bucket
    int stride = mean + mean / 8 + 512;    // ~ +20 sigma slack, overflow-guarded

    char* w = (char*)d_ws;
    auto alloc = [&](size_t bytes) {
        char* p = w;
        w += (bytes + 255) & ~(size_t)255;
        return p;
    };
    int* cnt     = (int*)alloc((size_t)N * 4);
    int* row     = (int*)alloc((size_t)N * 4);
    int* list    = (int*)alloc((size_t)N * 4);
    int* listctr = (int*)alloc(256);
    int* gcnt    = (int*)alloc(1024 * 4);
    int* col     = (int*)alloc((size_t)NB * stride * 4);
    unsigned short* h0   = (unsigned short*)alloc((size_t)N * H_DIM * 2);
    unsigned short* h1   = (unsigned short*)alloc((size_t)N * H_DIM * 2);
    unsigned short* aggb = (unsigned short*)alloc((size_t)N * H_DIM * 2);
    // ebuf's lifetime [scatter, build] strictly precedes h0/h1 use -> alias
    unsigned int* ebuf = (unsigned int*)h0;  // needs NB*stride*4 <= 2*N*64*2 bytes: 15MB <= 51MB ok

    hipMemsetAsync(gcnt, 0, 1024 * 4, stream);
    hipMemsetAsync(listctr, 0, 4, stream);

    k_scatter<<<(E + 256 * EPB - 1) / (256 * EPB), 256, 0, stream>>>(src, dst, E, NB, stride, gcnt, ebuf);
    k_build<<<NB, 1024, 0, stream>>>(ebuf, gcnt, stride, N, row, cnt, col, list, listctr);

    int tiles = (N + 15) / 16;
    int gblk = (tiles + 3) / 4;
    int ablk = ((size_t)N * 64 + 255) / 256;

    k_lin1<<<gblk, 256, 0, stream>>>(x, W1, b1, h0, N);

    k_agg<<<ablk, 256, 0, stream>>>(h0, row, cnt, col, aggb, N);
    k_bucket<<<gblk, 256, 0, stream>>>(aggb, relW, relb, fuse, 0, h0, h1, N);
    k_fixup<<<16, 256, 0, stream>>>(aggb, list, listctr, cnt, relW, relb, fuse, 0, h0, h1);

    k_agg<<<ablk, 256, 0, stream>>>(h1, row, cnt, col, aggb, N);
    k_bucket<<<gblk, 256, 0, stream>>>(aggb, relW, relb, fuse, 1, h0, h1, N);
    k_fixup<<<16, 256, 0, stream>>>(aggb, list, listctr, cnt, relW, relb, fuse, 1, h0, h1);

    k_out<<<gblk, 256, 0, stream>>>(h1, Wout, bout, out, N);
}

// Round 6
// 532.365 us; speedup vs baseline: 5.8698x; 1.0346x over previous
//
#include <hip/hip_runtime.h>
#include <cmath>
#include <cstddef>

#define F_IN 128
#define H_DIM 64
#define C_OUT 40
#define MAXDEG 5
#define EPB 16

typedef __attribute__((ext_vector_type(8))) _Float16 half8;
typedef __attribute__((ext_vector_type(4))) _Float16 half4;
typedef __attribute__((ext_vector_type(4))) float fv4;

__device__ __forceinline__ half4 u2h(uint2 u) { return __builtin_bit_cast(half4, u); }
__device__ __forceinline__ uint2 h2u(half4 v) { return __builtin_bit_cast(uint2, v); }

// ============ CSR build: fixed-stride 1024-node buckets ============
// bucket b = dst >> 10; packed edge = (dst&1023)<<20 | src  (needs src < 2^20)

__global__ __launch_bounds__(256) void k_scatter(const int* __restrict__ src,
                                                 const int* __restrict__ dst,
                                                 int E, int NB, int stride,
                                                 int* __restrict__ gcnt,
                                                 unsigned int* __restrict__ ebuf) {
    __shared__ int hist[256];
    __shared__ int base[256];
    int tid = threadIdx.x;
    if (tid < NB) hist[tid] = 0;
    __syncthreads();
    int e0 = blockIdx.x * (256 * EPB);
    int es[EPB], ed[EPB];
#pragma unroll
    for (int i = 0; i < EPB; ++i) {
        int e = e0 + i * 256 + tid;
        int s = -1, d = -1;
        if (e < E) { s = src[e]; d = dst[e]; }
        es[i] = s; ed[i] = d;
        if (d >= 0 && s != d) atomicAdd(&hist[d >> 10], 1);
    }
    __syncthreads();
    if (tid < NB) {
        int c = hist[tid];
        base[tid] = c ? atomicAdd(&gcnt[tid], c) : 0;
        hist[tid] = 0;
    }
    __syncthreads();
#pragma unroll
    for (int i = 0; i < EPB; ++i) {
        int s = es[i], d = ed[i];
        if (d >= 0 && s != d) {
            int b = d >> 10;
            int p = base[b] + atomicAdd(&hist[b], 1);
            if (p < stride)
                ebuf[(size_t)b * stride + p] = ((unsigned)(d & 1023) << 20) | (unsigned)s;
        }
    }
}

__global__ __launch_bounds__(1024) void k_build(const unsigned int* __restrict__ ebuf,
                                                const int* __restrict__ gcnt, int stride, int N,
                                                int* __restrict__ row, int* __restrict__ cnt,
                                                int* __restrict__ col, int* __restrict__ list,
                                                int* __restrict__ listctr) {
    __shared__ int lcnt[1024];
    __shared__ int lcur[1024];
    int bk = blockIdx.x;
    int n0 = bk << 10;
    int tid = threadIdx.x;
    int ebase = bk * stride;
    int ec = min(gcnt[bk], stride);
    int eend = ebase + ec;
    lcnt[tid] = 0;
    __syncthreads();
    for (int e = ebase + tid; e < eend; e += 1024)
        atomicAdd(&lcnt[ebuf[e] >> 20], 1);
    __syncthreads();
    int v = lcnt[tid];
    lcur[tid] = v;
    __syncthreads();
    for (int off = 1; off < 1024; off <<= 1) {
        int t = (tid >= off) ? lcur[tid - off] : 0;
        __syncthreads();
        lcur[tid] += t;
        __syncthreads();
    }
    int ex = lcur[tid] - v;
    __syncthreads();
    lcur[tid] = ebase + ex;
    int n = n0 + tid;
    if (n < N) {
        row[n] = ebase + ex;
        cnt[n] = v;
        if (v < MAXDEG) {
            int p = atomicAdd(listctr, 1);
            list[p] = n;
        }
    }
    __syncthreads();
    for (int e = ebase + tid; e < eend; e += 1024) {
        unsigned edv = ebuf[e];
        int dl = edv >> 20;
        int p = atomicAdd(&lcur[dl], 1);
        col[p] = (int)(edv & 0xFFFFF);
    }
}

// ---------------- h0 = relu(x @ W1 + b1), MFMA f16 ----------------
__global__ __launch_bounds__(256) void k_lin1(const float* __restrict__ x,
                                              const float* __restrict__ W1,
                                              const float* __restrict__ b1,
                                              _Float16* __restrict__ h, int N) {
    __shared__ _Float16 Wl[4 * 4 * 64 * 8];
    int tid = threadIdx.x;
    for (int idx = tid; idx < 4 * 4 * 64 * 8; idx += 256) {
        int j = idx & 7, ln = (idx >> 3) & 63, ks = (idx >> 9) & 3, t = idx >> 11;
        int k = ks * 32 + (ln >> 4) * 8 + j;
        int n = t * 16 + (ln & 15);
        Wl[idx] = (_Float16)W1[k * H_DIM + n];
    }
    __syncthreads();

    int wave = tid >> 6, lane = tid & 63;
    int tile = blockIdx.x * 4 + wave;
    int row0 = tile * 16;
    if (row0 >= N) return;
    int m = lane & 15, quad = lane >> 4;
    int row = row0 + m;
    if (row >= N) row = N - 1;

    half8 a[4];
    const float* xr = x + (size_t)row * F_IN + quad * 8;
#pragma unroll
    for (int ks = 0; ks < 4; ++ks) {
        fv4 lo = *(const fv4*)(xr + ks * 32);
        fv4 hi = *(const fv4*)(xr + ks * 32 + 4);
        half8 av;
#pragma unroll
        for (int j = 0; j < 4; ++j) av[j] = (_Float16)lo[j];
#pragma unroll
        for (int j = 0; j < 4; ++j) av[4 + j] = (_Float16)hi[j];
        a[ks] = av;
    }

    fv4 acc[4];
#pragma unroll
    for (int t = 0; t < 4; ++t) acc[t] = (fv4){0.f, 0.f, 0.f, 0.f};
#pragma unroll
    for (int ks = 0; ks < 4; ++ks) {
#pragma unroll
        for (int t = 0; t < 4; ++t) {
            half8 b = *(const half8*)&Wl[(((t * 4 + ks) * 64) + lane) * 8];
            acc[t] = __builtin_amdgcn_mfma_f32_16x16x32_f16(a[ks], b, acc[t], 0, 0, 0);
        }
    }
#pragma unroll
    for (int t = 0; t < 4; ++t) {
        int n = t * 16 + m;
        float bias = b1[n];
#pragma unroll
        for (int reg = 0; reg < 4; ++reg) {
            int r = row0 + quad * 4 + reg;
            if (r < N) {
                float v = acc[t][reg] + bias;
                h[(size_t)r * H_DIM + n] = (_Float16)fmaxf(v, 0.f);
            }
        }
    }
}

// ---------------- agg[n] = h[n] + sum h[src], packed-f16 accumulate ----------------
// lane: g = lane>>4 (edge slot 0..3), f = lane&15 (uint2 index; features 4f..4f+3)
__global__ void k_agg(const _Float16* __restrict__ hin, const int* __restrict__ row,
                      const int* __restrict__ cnt, const int* __restrict__ col,
                      _Float16* __restrict__ agg, int N) {
    int gid = blockIdx.x * blockDim.x + threadIdx.x;
    int n = gid >> 6, lane = gid & 63;
    if (n >= N) return;
    int g = lane >> 4;
    int f = lane & 15;
    int base = row[n];
    int c = cnt[n];
    const uint2* hv = (const uint2*)hin;   // row stride 16 uint2
    half4 acc = u2h((uint2){0u, 0u});
    for (int j0 = 0; j0 < c; j0 += 64) {
        int idx = j0 + lane;
        int myc = (idx < c) ? col[base + idx] : 0;
        int mm = min(64, c - j0);
        int t = 0;
        for (; t + 8 <= mm; t += 8) {
            int s0 = __shfl(myc, t + g);
            int s1 = __shfl(myc, t + 4 + g);
            uint2 u0 = hv[(size_t)s0 * 16 + f];
            uint2 u1 = hv[(size_t)s1 * 16 + f];
            acc += u2h(u0);
            acc += u2h(u1);
        }
        for (; t < mm; t += 4) {
            int e = t + g;
            bool val = (e < mm);
            int s = __shfl(myc, val ? e : 0);
            uint2 u = hv[(size_t)(val ? s : n) * 16 + f];
            if (!val) u = (uint2){0u, 0u};
            acc += u2h(u);
        }
    }
    // reduce across the 4 edge slots
    {
        uint2 t1 = h2u(acc);
        t1.x = __shfl_xor(t1.x, 16); t1.y = __shfl_xor(t1.y, 16);
        acc += u2h(t1);
        uint2 t2 = h2u(acc);
        t2.x = __shfl_xor(t2.x, 32); t2.y = __shfl_xor(t2.y, 32);
        acc += u2h(t2);
    }
    // self term
    acc += u2h(hv[(size_t)n * 16 + f]);
    if (g == 0)
        ((uint2*)agg)[(size_t)n * 16 + f] = h2u(acc);
}

// ---------------- bucket-5 GEMM for ALL nodes (f16 MFMA) ----------------
__global__ __launch_bounds__(256) void k_bucket(const _Float16* __restrict__ agg,
                                                const float* __restrict__ relW,
                                                const float* __restrict__ relb,
                                                const float* __restrict__ fuse, int layer,
                                                const _Float16* __restrict__ xfirst,
                                                _Float16* __restrict__ h, int N) {
    __shared__ _Float16 Wl[4 * 2 * 64 * 8];
    const float* W = relW + (size_t)(layer * 6 + MAXDEG) * (H_DIM * H_DIM);
    int tid = threadIdx.x;
    for (int idx = tid; idx < 4 * 2 * 64 * 8; idx += 256) {
        int j = idx & 7, ln = (idx >> 3) & 63, ks = (idx >> 9) & 1, t = idx >> 10;
        int k = ks * 32 + (ln >> 4) * 8 + j;
        int n = t * 16 + (ln & 15);
        Wl[idx] = (_Float16)W[k * H_DIM + n];
    }
    __syncthreads();

    int wave = tid >> 6, lane = tid & 63;
    int tile = blockIdx.x * 4 + wave;
    int row0 = tile * 16;
    if (row0 >= N) return;
    int m = lane & 15, quad = lane >> 4;
    int row = row0 + m;
    if (row >= N) row = N - 1;

    half8 a[2];
#pragma unroll
    for (int ks = 0; ks < 2; ++ks)
        a[ks] = *(const half8*)(agg + (size_t)row * H_DIM + ks * 32 + quad * 8);

    fv4 acc[4];
#pragma unroll
    for (int t = 0; t < 4; ++t) acc[t] = (fv4){0.f, 0.f, 0.f, 0.f};
#pragma unroll
    for (int ks = 0; ks < 2; ++ks) {
#pragma unroll
        for (int t = 0; t < 4; ++t) {
            half8 b = *(const half8*)&Wl[(((t * 2 + ks) * 64) + lane) * 8];
            acc[t] = __builtin_amdgcn_mfma_f32_16x16x32_f16(a[ks], b, acc[t], 0, 0, 0);
        }
    }
    float fu = fuse[layer];
    const float* bias = relb + (layer * 6 + MAXDEG) * H_DIM;
#pragma unroll
    for (int t = 0; t < 4; ++t) {
        int n = t * 16 + m;
        float bv = bias[n];
#pragma unroll
        for (int reg = 0; reg < 4; ++reg) {
            int r = row0 + quad * 4 + reg;
            if (r < N) {
                float v = acc[t][reg] + bv + fu * (float)xfirst[(size_t)r * H_DIM + n];
                h[(size_t)r * H_DIM + n] = (_Float16)v;
            }
        }
    }
}

// ---------------- fixup for rare deg<5 nodes ----------------
__global__ void k_fixup(const _Float16* __restrict__ agg, const int* __restrict__ list,
                        const int* __restrict__ listctr, const int* __restrict__ cnt,
                        const float* __restrict__ relW, const float* __restrict__ relb,
                        const float* __restrict__ fuse, int layer,
                        const _Float16* __restrict__ xfirst,
                        _Float16* __restrict__ h) {
    int gid = blockIdx.x * blockDim.x + threadIdx.x;
    int wave = gid >> 6, lane = gid & 63;
    int nwaves = (gridDim.x * blockDim.x) >> 6;
    int M = *listctr;
    float fu = fuse[layer];
    for (int i = wave; i < M; i += nwaves) {
        int n = list[i];
        int d = cnt[n];
        const float* W = relW + (size_t)(layer * 6 + d) * (H_DIM * H_DIM);
        float a = (float)agg[(size_t)n * H_DIM + lane];
        float acc = relb[(layer * 6 + d) * H_DIM + lane];
#pragma unroll 16
        for (int k = 0; k < 64; ++k)
            acc = fmaf(__shfl(a, k), W[k * H_DIM + lane], acc);
        acc += fu * (float)xfirst[(size_t)n * H_DIM + lane];
        h[(size_t)n * H_DIM + lane] = (_Float16)acc;
    }
}

// ---------------- logits + log_softmax via MFMA (f16) ----------------
__global__ __launch_bounds__(256) void k_out(const _Float16* __restrict__ h,
                                             const float* __restrict__ Wout,
                                             const float* __restrict__ bout,
                                             float* __restrict__ out, int N) {
    __shared__ _Float16 Wl[3 * 2 * 64 * 8];
    int tid = threadIdx.x;
    for (int idx = tid; idx < 3 * 2 * 64 * 8; idx += 256) {
        int j = idx & 7, ln = (idx >> 3) & 63, ks = (idx >> 9) & 1, t = idx >> 10;
        int k = ks * 32 + (ln >> 4) * 8 + j;
        int n = t * 16 + (ln & 15);
        Wl[idx] = (n < C_OUT) ? (_Float16)Wout[k * C_OUT + n] : (_Float16)0.f;
    }
    __syncthreads();

    int wave = tid >> 6, lane = tid & 63;
    int tile = blockIdx.x * 4 + wave;
    int row0 = tile * 16;
    if (row0 >= N) return;
    int m = lane & 15, quad = lane >> 4;
    int row = row0 + m;
    if (row >= N) row = N - 1;

    half8 a[2];
#pragma unroll
    for (int ks = 0; ks < 2; ++ks)
        a[ks] = *(const half8*)(h + (size_t)row * H_DIM + ks * 32 + quad * 8);

    fv4 acc[3];
#pragma unroll
    for (int t = 0; t < 3; ++t) acc[t] = (fv4){0.f, 0.f, 0.f, 0.f};
#pragma unroll
    for (int ks = 0; ks < 2; ++ks) {
#pragma unroll
        for (int t = 0; t < 3; ++t) {
            half8 b = *(const half8*)&Wl[(((t * 2 + ks) * 64) + lane) * 8];
            acc[t] = __builtin_amdgcn_mfma_f32_16x16x32_f16(a[ks], b, acc[t], 0, 0, 0);
        }
    }
    bool v2 = (m < 8);
    float b0 = bout[m], b1v = bout[16 + m], b2v = v2 ? bout[32 + m] : 0.f;
#pragma unroll
    for (int reg = 0; reg < 4; ++reg) {
        int r = row0 + quad * 4 + reg;
        float l0 = acc[0][reg] + b0;
        float l1 = acc[1][reg] + b1v;
        float l2 = v2 ? (acc[2][reg] + b2v) : -INFINITY;
        float mx = fmaxf(fmaxf(l0, l1), l2);
#pragma unroll
        for (int off = 1; off < 16; off <<= 1) mx = fmaxf(mx, __shfl_xor(mx, off));
        float s = expf(l0 - mx) + expf(l1 - mx) + (v2 ? expf(l2 - mx) : 0.f);
#pragma unroll
        for (int off = 1; off < 16; off <<= 1) s += __shfl_xor(s, off);
        float ls = logf(s);
        if (r < N) {
            out[(size_t)r * C_OUT + m] = l0 - mx - ls;
            out[(size_t)r * C_OUT + 16 + m] = l1 - mx - ls;
            if (v2) out[(size_t)r * C_OUT + 32 + m] = l2 - mx - ls;
        }
    }
}

extern "C" void kernel_launch(void* const* d_in, const int* in_sizes, int n_in,
                              void* d_out, int out_size, void* d_ws, size_t ws_size,
                              hipStream_t stream) {
    const float* x    = (const float*)d_in[0];
    const int*   ei   = (const int*)d_in[1];
    const float* W1   = (const float*)d_in[2];
    const float* b1   = (const float*)d_in[3];
    const float* relW = (const float*)d_in[4];
    const float* relb = (const float*)d_in[5];
    const float* Wout = (const float*)d_in[6];
    const float* bout = (const float*)d_in[7];
    const float* fuse = (const float*)d_in[8];
    float* out = (float*)d_out;

    int N = in_sizes[0] / F_IN;
    int E = in_sizes[1] / 2;
    const int* src = ei;
    const int* dst = ei + E;
    int NB = (N + 1023) >> 10;
    int mean = (E + NB - 1) / NB;
    int stride = mean + mean / 8 + 512;

    char* w = (char*)d_ws;
    auto alloc = [&](size_t bytes) {
        char* p = w;
        w += (bytes + 255) & ~(size_t)255;
        return p;
    };
    int* cnt     = (int*)alloc((size_t)N * 4);
    int* row     = (int*)alloc((size_t)N * 4);
    int* list    = (int*)alloc((size_t)N * 4);
    int* listctr = (int*)alloc(256);
    int* gcnt    = (int*)alloc(1024 * 4);
    int* col     = (int*)alloc((size_t)NB * stride * 4);
    _Float16* h0   = (_Float16*)alloc((size_t)N * H_DIM * 2);
    _Float16* h1   = (_Float16*)alloc((size_t)N * H_DIM * 2);
    _Float16* aggb = (_Float16*)alloc((size_t)N * H_DIM * 2);
    unsigned int* ebuf = (unsigned int*)h0;  // ebuf dead before lin1 writes h0

    hipMemsetAsync(gcnt, 0, 1024 * 4, stream);
    hipMemsetAsync(listctr, 0, 4, stream);

    k_scatter<<<(E + 256 * EPB - 1) / (256 * EPB), 256, 0, stream>>>(src, dst, E, NB, stride, gcnt, ebuf);
    k_build<<<NB, 1024, 0, stream>>>(ebuf, gcnt, stride, N, row, cnt, col, list, listctr);

    int tiles = (N + 15) / 16;
    int gblk = (tiles + 3) / 4;
    int ablk = ((size_t)N * 64 + 255) / 256;

    k_lin1<<<gblk, 256, 0, stream>>>(x, W1, b1, h0, N);

    k_agg<<<ablk, 256, 0, stream>>>(h0, row, cnt, col, aggb, N);
    k_bucket<<<gblk, 256, 0, stream>>>(aggb, relW, relb, fuse, 0, h0, h1, N);
    k_fixup<<<16, 256, 0, stream>>>(aggb, list, listctr, cnt, relW, relb, fuse, 0, h0, h1);

    k_agg<<<ablk, 256, 0, stream>>>(h1, row, cnt, col, aggb, N);
    k_bucket<<<gblk, 256, 0, stream>>>(aggb, relW, relb, fuse, 1, h0, h1, N);
    k_fixup<<<16, 256, 0, stream>>>(aggb, list, listctr, cnt, relW, relb, fuse, 1, h0, h1);

    k_out<<<gblk, 256, 0, stream>>>(h1, Wout, bout, out, N);
}

// Round 7
// 460.986 us; speedup vs baseline: 6.7786x; 1.1548x over previous
//
#include <hip/hip_runtime.h>
#include <cmath>
#include <cstddef>

#define F_IN 128
#define H_DIM 64
#define C_OUT 40
#define MAXDEG 5
#define EPB 16

typedef __attribute__((ext_vector_type(8))) _Float16 half8;
typedef __attribute__((ext_vector_type(4))) _Float16 half4;
typedef __attribute__((ext_vector_type(4))) float fv4;

__device__ __forceinline__ half4 u2h(uint2 u) { return __builtin_bit_cast(half4, u); }
__device__ __forceinline__ uint2 h2u(half4 v) { return __builtin_bit_cast(uint2, v); }

// ============ CSR build: fixed-stride 512-node buckets ============
// bucket b = dst >> 9; packed edge = (dst&511)<<20 | src  (needs src < 2^20)

__global__ __launch_bounds__(256) void k_scatter(const int* __restrict__ src,
                                                 const int* __restrict__ dst,
                                                 int E, int NB, int stride,
                                                 int* __restrict__ gcnt,
                                                 unsigned int* __restrict__ ebuf) {
    __shared__ int hist[512];
    __shared__ int base[512];
    int tid = threadIdx.x;
    for (int i = tid; i < NB; i += 256) hist[i] = 0;
    __syncthreads();
    int e0 = blockIdx.x * (256 * EPB);
    int es[EPB], ed[EPB];
#pragma unroll
    for (int i = 0; i < EPB; ++i) {
        int e = e0 + i * 256 + tid;
        int s = -1, d = -1;
        if (e < E) { s = src[e]; d = dst[e]; }
        es[i] = s; ed[i] = d;
        if (d >= 0 && s != d) atomicAdd(&hist[d >> 9], 1);
    }
    __syncthreads();
    for (int i = tid; i < NB; i += 256) {
        int c = hist[i];
        base[i] = c ? atomicAdd(&gcnt[i], c) : 0;
        hist[i] = 0;
    }
    __syncthreads();
#pragma unroll
    for (int i = 0; i < EPB; ++i) {
        int s = es[i], d = ed[i];
        if (d >= 0 && s != d) {
            int b = d >> 9;
            int p = base[b] + atomicAdd(&hist[b], 1);
            if (p < stride)
                ebuf[(size_t)b * stride + p] = ((unsigned)(d & 511) << 20) | (unsigned)s;
        }
    }
}

__global__ __launch_bounds__(512) void k_build(const unsigned int* __restrict__ ebuf,
                                               const int* __restrict__ gcnt, int stride, int N,
                                               int* __restrict__ row, int* __restrict__ cnt,
                                               int* __restrict__ col) {
    __shared__ int lcnt[512];
    __shared__ int lcur[512];
    int bk = blockIdx.x;
    int n0 = bk << 9;
    int tid = threadIdx.x;
    int ebase = bk * stride;
    int ec = min(gcnt[bk], stride);
    int eend = ebase + ec;
    lcnt[tid] = 0;
    __syncthreads();
    for (int e = ebase + tid; e < eend; e += 512)
        atomicAdd(&lcnt[ebuf[e] >> 20], 1);
    __syncthreads();
    int v = lcnt[tid];
    lcur[tid] = v;
    __syncthreads();
    for (int off = 1; off < 512; off <<= 1) {
        int t = (tid >= off) ? lcur[tid - off] : 0;
        __syncthreads();
        lcur[tid] += t;
        __syncthreads();
    }
    int ex = lcur[tid] - v;
    __syncthreads();
    lcur[tid] = ebase + ex;
    int n = n0 + tid;
    if (n < N) {
        row[n] = ebase + ex;
        cnt[n] = v;
    }
    __syncthreads();
    for (int e = ebase + tid; e < eend; e += 512) {
        unsigned edv = ebuf[e];
        int dl = edv >> 20;
        int p = atomicAdd(&lcur[dl], 1);
        col[p] = (int)(edv & 0xFFFFF);
    }
}

// ---------------- h0 = relu(x @ W1 + b1), MFMA f16; also zeroes row N of h0,h1 ----------------
__global__ __launch_bounds__(256) void k_lin1(const float* __restrict__ x,
                                              const float* __restrict__ W1,
                                              const float* __restrict__ b1,
                                              _Float16* __restrict__ h,
                                              _Float16* __restrict__ hz2, int N) {
    __shared__ _Float16 Wl[4 * 4 * 64 * 8];
    int tid = threadIdx.x;
    if (blockIdx.x == 0 && tid < 64) {   // zero rows used by gather's inactive slots
        h[(size_t)N * H_DIM + tid] = (_Float16)0.f;
        hz2[(size_t)N * H_DIM + tid] = (_Float16)0.f;
    }
    for (int idx = tid; idx < 4 * 4 * 64 * 8; idx += 256) {
        int j = idx & 7, ln = (idx >> 3) & 63, ks = (idx >> 9) & 3, t = idx >> 11;
        int k = ks * 32 + (ln >> 4) * 8 + j;
        int n = t * 16 + (ln & 15);
        Wl[idx] = (_Float16)W1[k * H_DIM + n];
    }
    __syncthreads();

    int wave = tid >> 6, lane = tid & 63;
    int tile = blockIdx.x * 4 + wave;
    int row0 = tile * 16;
    if (row0 >= N) return;
    int m = lane & 15, quad = lane >> 4;
    int row = row0 + m;
    if (row >= N) row = N - 1;

    half8 a[4];
    const float* xr = x + (size_t)row * F_IN + quad * 8;
#pragma unroll
    for (int ks = 0; ks < 4; ++ks) {
        fv4 lo = *(const fv4*)(xr + ks * 32);
        fv4 hi = *(const fv4*)(xr + ks * 32 + 4);
        half8 av;
#pragma unroll
        for (int j = 0; j < 4; ++j) av[j] = (_Float16)lo[j];
#pragma unroll
        for (int j = 0; j < 4; ++j) av[4 + j] = (_Float16)hi[j];
        a[ks] = av;
    }

    fv4 acc[4];
#pragma unroll
    for (int t = 0; t < 4; ++t) acc[t] = (fv4){0.f, 0.f, 0.f, 0.f};
#pragma unroll
    for (int ks = 0; ks < 4; ++ks) {
#pragma unroll
        for (int t = 0; t < 4; ++t) {
            half8 b = *(const half8*)&Wl[(((t * 4 + ks) * 64) + lane) * 8];
            acc[t] = __builtin_amdgcn_mfma_f32_16x16x32_f16(a[ks], b, acc[t], 0, 0, 0);
        }
    }
#pragma unroll
    for (int t = 0; t < 4; ++t) {
        int n = t * 16 + m;
        float bias = b1[n];
#pragma unroll
        for (int reg = 0; reg < 4; ++reg) {
            int r = row0 + quad * 4 + reg;
            if (r < N) {
                float v = acc[t][reg] + bias;
                h[(size_t)r * H_DIM + n] = (_Float16)fmaxf(v, 0.f);
            }
        }
    }
}

// ---------------- agg: 4 nodes/wave (16 lanes each), packed-f16, zero-row masking -------
__global__ void k_agg(const _Float16* __restrict__ hin, const int* __restrict__ row,
                      const int* __restrict__ cnt, const int* __restrict__ col,
                      _Float16* __restrict__ agg, int N) {
    int wid = (blockIdx.x * blockDim.x + threadIdx.x) >> 6;
    int lane = threadIdx.x & 63;
    int g = lane >> 4, fl = lane & 15, gl = g << 4;
    int n = wid * 4 + g;
    bool nv = (n < N);
    int nn = nv ? n : (N - 1);
    int base = row[nn];
    int c = nv ? cnt[nn] : 0;
    const uint2* hv = (const uint2*)hin;   // row stride 16 uint2; row N is zeros
    int cmax = c;
    cmax = max(cmax, __shfl_xor(cmax, 16));
    cmax = max(cmax, __shfl_xor(cmax, 32));
    half4 acc = u2h((uint2){0u, 0u});
    for (int j0 = 0; j0 < cmax; j0 += 16) {
        int idx = j0 + fl;
        int myc = (idx < c) ? col[base + idx] : N;   // N = zero row
        int tmax = min(16, cmax - j0);
        int t = 0;
        for (; t + 4 <= tmax; t += 4) {
            int s0 = __shfl(myc, gl + t);
            int s1 = __shfl(myc, gl + t + 1);
            int s2 = __shfl(myc, gl + t + 2);
            int s3 = __shfl(myc, gl + t + 3);
            uint2 u0 = hv[(size_t)s0 * 16 + fl];
            uint2 u1 = hv[(size_t)s1 * 16 + fl];
            uint2 u2 = hv[(size_t)s2 * 16 + fl];
            uint2 u3 = hv[(size_t)s3 * 16 + fl];
            half4 p01 = u2h(u0) + u2h(u1);
            half4 p23 = u2h(u2) + u2h(u3);
            acc += (p01 + p23);
        }
        for (; t < tmax; ++t) {
            int s = __shfl(myc, gl + t);
            acc += u2h(hv[(size_t)s * 16 + fl]);
        }
    }
    acc += u2h(hv[(size_t)nn * 16 + fl]);   // self term
    if (nv)
        ((uint2*)agg)[(size_t)nn * 16 + fl] = h2u(acc);
}

// ---------------- layer-0: bucket-5 GEMM + residual + inline deg<5 fixup ----------------
__global__ __launch_bounds__(256) void k_bucket(const _Float16* __restrict__ agg,
                                                const int* __restrict__ cnt,
                                                const float* __restrict__ relW,
                                                const float* __restrict__ relb,
                                                const float* __restrict__ fuse, int layer,
                                                const _Float16* __restrict__ xfirst,
                                                _Float16* __restrict__ h, int N) {
    __shared__ _Float16 Wl[4 * 2 * 64 * 8];
    __shared__ int flist[64];
    __shared__ int fn;
    const float* W = relW + (size_t)(layer * 6 + MAXDEG) * (H_DIM * H_DIM);
    int tid = threadIdx.x;
    if (tid == 0) fn = 0;
    for (int idx = tid; idx < 4 * 2 * 64 * 8; idx += 256) {
        int j = idx & 7, ln = (idx >> 3) & 63, ks = (idx >> 9) & 1, t = idx >> 10;
        int k = ks * 32 + (ln >> 4) * 8 + j;
        int n = t * 16 + (ln & 15);
        Wl[idx] = (_Float16)W[k * H_DIM + n];
    }
    __syncthreads();

    int wave = tid >> 6, lane = tid & 63;
    int row0 = blockIdx.x * 64 + wave * 16;
    int m = lane & 15, quad = lane >> 4;
    int row = row0 + m;
    if (row >= N) row = N - 1;
    float fu = fuse[layer];
    const float* bias = relb + (layer * 6 + MAXDEG) * H_DIM;

    half8 a[2];
#pragma unroll
    for (int ks = 0; ks < 2; ++ks)
        a[ks] = *(const half8*)(agg + (size_t)row * H_DIM + ks * 32 + quad * 8);

    fv4 acc[4];
#pragma unroll
    for (int t = 0; t < 4; ++t) acc[t] = (fv4){0.f, 0.f, 0.f, 0.f};
#pragma unroll
    for (int ks = 0; ks < 2; ++ks)
#pragma unroll
        for (int t = 0; t < 4; ++t) {
            half8 b = *(const half8*)&Wl[(((t * 2 + ks) * 64) + lane) * 8];
            acc[t] = __builtin_amdgcn_mfma_f32_16x16x32_f16(a[ks], b, acc[t], 0, 0, 0);
        }

    int cr[4];
#pragma unroll
    for (int reg = 0; reg < 4; ++reg) {
        int r = row0 + quad * 4 + reg;
        cr[reg] = (r < N) ? cnt[r] : MAXDEG;
    }
    if (m == 0) {
#pragma unroll
        for (int reg = 0; reg < 4; ++reg) {
            int r = row0 + quad * 4 + reg;
            if (r < N && cr[reg] < MAXDEG) {
                int p = atomicAdd(&fn, 1);
                if (p < 64) flist[p] = wave * 16 + quad * 4 + reg;
            }
        }
    }
#pragma unroll
    for (int t = 0; t < 4; ++t) {
        int n = t * 16 + m;
        float bv = bias[n];
#pragma unroll
        for (int reg = 0; reg < 4; ++reg) {
            int r = row0 + quad * 4 + reg;
            if (r < N && cr[reg] >= MAXDEG) {
                float v = acc[t][reg] + bv + fu * (float)xfirst[(size_t)r * H_DIM + n];
                h[(size_t)r * H_DIM + n] = (_Float16)v;
            }
        }
    }
    __syncthreads();
    int M = min(fn, 64);
    for (int i = wave; i < M; i += 4) {
        int rl = flist[i];
        int r = blockIdx.x * 64 + rl;
        int d = cnt[r];
        const float* Wd = relW + (size_t)(layer * 6 + d) * (H_DIM * H_DIM);
        float av = (float)agg[(size_t)r * H_DIM + lane];
        float accf = relb[(layer * 6 + d) * H_DIM + lane];
        for (int k = 0; k < 64; ++k)
            accf = fmaf(__shfl(av, k), Wd[k * H_DIM + lane], accf);
        accf += fu * (float)xfirst[(size_t)r * H_DIM + lane];
        h[(size_t)r * H_DIM + lane] = (_Float16)accf;
    }
}

// ---------------- layer-1 fused: bucket GEMM + residual + fixup + logits + log_softmax --
#define HB 80   // hbuf row stride in f16 (16B-aligned, bank-staggered)
__global__ __launch_bounds__(256) void k_bucket_out(const _Float16* __restrict__ agg,
                                                    const int* __restrict__ cnt,
                                                    const float* __restrict__ relW,
                                                    const float* __restrict__ relb,
                                                    const float* __restrict__ fuse,
                                                    const _Float16* __restrict__ xfirst,
                                                    const float* __restrict__ Wout,
                                                    const float* __restrict__ bout,
                                                    float* __restrict__ out, int N) {
    __shared__ _Float16 Wl[4 * 2 * 64 * 8];
    __shared__ _Float16 Wo[3 * 2 * 64 * 8];
    __shared__ _Float16 hbuf[64 * HB];
    __shared__ int flist[64];
    __shared__ int fn;
    const int layer = 1;
    const float* W = relW + (size_t)(layer * 6 + MAXDEG) * (H_DIM * H_DIM);
    int tid = threadIdx.x;
    if (tid == 0) fn = 0;
    for (int idx = tid; idx < 4 * 2 * 64 * 8; idx += 256) {
        int j = idx & 7, ln = (idx >> 3) & 63, ks = (idx >> 9) & 1, t = idx >> 10;
        int k = ks * 32 + (ln >> 4) * 8 + j;
        int n = t * 16 + (ln & 15);
        Wl[idx] = (_Float16)W[k * H_DIM + n];
    }
    for (int idx = tid; idx < 3 * 2 * 64 * 8; idx += 256) {
        int j = idx & 7, ln = (idx >> 3) & 63, ks = (idx >> 9) & 1, t = idx >> 10;
        int k = ks * 32 + (ln >> 4) * 8 + j;
        int n = t * 16 + (ln & 15);
        Wo[idx] = (n < C_OUT) ? (_Float16)Wout[k * C_OUT + n] : (_Float16)0.f;
    }
    __syncthreads();

    int wave = tid >> 6, lane = tid & 63;
    int row0 = blockIdx.x * 64 + wave * 16;
    int m = lane & 15, quad = lane >> 4;
    int row = row0 + m;
    if (row >= N) row = N - 1;
    float fu = fuse[layer];
    const float* bias = relb + (layer * 6 + MAXDEG) * H_DIM;

    half8 a[2];
#pragma unroll
    for (int ks = 0; ks < 2; ++ks)
        a[ks] = *(const half8*)(agg + (size_t)row * H_DIM + ks * 32 + quad * 8);

    fv4 acc[4];
#pragma unroll
    for (int t = 0; t < 4; ++t) acc[t] = (fv4){0.f, 0.f, 0.f, 0.f};
#pragma unroll
    for (int ks = 0; ks < 2; ++ks)
#pragma unroll
        for (int t = 0; t < 4; ++t) {
            half8 b = *(const half8*)&Wl[(((t * 2 + ks) * 64) + lane) * 8];
            acc[t] = __builtin_amdgcn_mfma_f32_16x16x32_f16(a[ks], b, acc[t], 0, 0, 0);
        }

    int cr[4];
#pragma unroll
    for (int reg = 0; reg < 4; ++reg) {
        int r = row0 + quad * 4 + reg;
        cr[reg] = (r < N) ? cnt[r] : MAXDEG;
    }
    if (m == 0) {
#pragma unroll
        for (int reg = 0; reg < 4; ++reg) {
            int r = row0 + quad * 4 + reg;
            if (r < N && cr[reg] < MAXDEG) {
                int p = atomicAdd(&fn, 1);
                if (p < 64) flist[p] = wave * 16 + quad * 4 + reg;
            }
        }
    }
    // write h tile into LDS (C-layout scatter)
#pragma unroll
    for (int t = 0; t < 4; ++t) {
        int n = t * 16 + m;
        float bv = bias[n];
#pragma unroll
        for (int reg = 0; reg < 4; ++reg) {
            int r = row0 + quad * 4 + reg;
            int rc = (r < N) ? r : (N - 1);
            float v = acc[t][reg] + bv + fu * (float)xfirst[(size_t)rc * H_DIM + n];
            int rl = wave * 16 + quad * 4 + reg;
            hbuf[rl * HB + n] = (_Float16)v;
        }
    }
    __syncthreads();
    int M = min(fn, 64);
    for (int i = wave; i < M; i += 4) {
        int rl = flist[i];
        int r = blockIdx.x * 64 + rl;
        int d = cnt[r];
        const float* Wd = relW + (size_t)(layer * 6 + d) * (H_DIM * H_DIM);
        float av = (float)agg[(size_t)r * H_DIM + lane];
        float accf = relb[(layer * 6 + d) * H_DIM + lane];
        for (int k = 0; k < 64; ++k)
            accf = fmaf(__shfl(av, k), Wd[k * H_DIM + lane], accf);
        accf += fu * (float)xfirst[(size_t)r * H_DIM + lane];
        hbuf[rl * HB + lane] = (_Float16)accf;
    }
    __syncthreads();

    // logits: A-frags from hbuf
    half8 ao[2];
#pragma unroll
    for (int ks = 0; ks < 2; ++ks)
        ao[ks] = *(const half8*)&hbuf[(wave * 16 + m) * HB + ks * 32 + quad * 8];

    fv4 lacc[3];
#pragma unroll
    for (int t = 0; t < 3; ++t) lacc[t] = (fv4){0.f, 0.f, 0.f, 0.f};
#pragma unroll
    for (int ks = 0; ks < 2; ++ks)
#pragma unroll
        for (int t = 0; t < 3; ++t) {
            half8 b = *(const half8*)&Wo[(((t * 2 + ks) * 64) + lane) * 8];
            lacc[t] = __builtin_amdgcn_mfma_f32_16x16x32_f16(ao[ks], b, lacc[t], 0, 0, 0);
        }
    bool v2 = (m < 8);
    float b0 = bout[m], b1v = bout[16 + m], b2v = v2 ? bout[32 + m] : 0.f;
#pragma unroll
    for (int reg = 0; reg < 4; ++reg) {
        int r = row0 + quad * 4 + reg;
        float l0 = lacc[0][reg] + b0;
        float l1 = lacc[1][reg] + b1v;
        float l2 = v2 ? (lacc[2][reg] + b2v) : -INFINITY;
        float mx = fmaxf(fmaxf(l0, l1), l2);
#pragma unroll
        for (int off = 1; off < 16; off <<= 1) mx = fmaxf(mx, __shfl_xor(mx, off));
        float s = expf(l0 - mx) + expf(l1 - mx) + (v2 ? expf(l2 - mx) : 0.f);
#pragma unroll
        for (int off = 1; off < 16; off <<= 1) s += __shfl_xor(s, off);
        float ls = logf(s);
        if (r < N) {
            out[(size_t)r * C_OUT + m] = l0 - mx - ls;
            out[(size_t)r * C_OUT + 16 + m] = l1 - mx - ls;
            if (v2) out[(size_t)r * C_OUT + 32 + m] = l2 - mx - ls;
        }
    }
}

extern "C" void kernel_launch(void* const* d_in, const int* in_sizes, int n_in,
                              void* d_out, int out_size, void* d_ws, size_t ws_size,
                              hipStream_t stream) {
    const float* x    = (const float*)d_in[0];
    const int*   ei   = (const int*)d_in[1];
    const float* W1   = (const float*)d_in[2];
    const float* b1   = (const float*)d_in[3];
    const float* relW = (const float*)d_in[4];
    const float* relb = (const float*)d_in[5];
    const float* Wout = (const float*)d_in[6];
    const float* bout = (const float*)d_in[7];
    const float* fuse = (const float*)d_in[8];
    float* out = (float*)d_out;

    int N = in_sizes[0] / F_IN;
    int E = in_sizes[1] / 2;
    const int* src = ei;
    const int* dst = ei + E;
    int NB = (N + 511) >> 9;               // 512-node buckets (needs N <= 262144)
    int mean = (E + NB - 1) / NB;
    int stride = mean + mean / 8 + 512;    // ~+20 sigma slack, overflow-guarded

    char* w = (char*)d_ws;
    auto alloc = [&](size_t bytes) {
        char* p = w;
        w += (bytes + 255) & ~(size_t)255;
        return p;
    };
    int* cnt  = (int*)alloc((size_t)N * 4);
    int* row  = (int*)alloc((size_t)N * 4);
    int* gcnt = (int*)alloc(1024 * 4);
    int* col  = (int*)alloc((size_t)NB * stride * 4);
    _Float16* h0   = (_Float16*)alloc((size_t)(N + 1) * H_DIM * 2);  // +1 zero row
    _Float16* h1   = (_Float16*)alloc((size_t)(N + 1) * H_DIM * 2);
    _Float16* aggb = (_Float16*)alloc((size_t)N * H_DIM * 2);
    unsigned int* ebuf = (unsigned int*)h0;  // ebuf dead before lin1 writes h0

    hipMemsetAsync(gcnt, 0, 1024 * 4, stream);

    k_scatter<<<(E + 256 * EPB - 1) / (256 * EPB), 256, 0, stream>>>(src, dst, E, NB, stride, gcnt, ebuf);
    k_build<<<NB, 512, 0, stream>>>(ebuf, gcnt, stride, N, row, cnt, col);

    int tiles = (N + 15) / 16;
    int gblk = (tiles + 3) / 4;
    int awaves = (N + 3) / 4;
    int ablk = (awaves * 64 + 255) / 256;

    k_lin1<<<gblk, 256, 0, stream>>>(x, W1, b1, h0, h1, N);

    k_agg<<<ablk, 256, 0, stream>>>(h0, row, cnt, col, aggb, N);
    k_bucket<<<gblk, 256, 0, stream>>>(aggb, cnt, relW, relb, fuse, 0, h0, h1, N);

    k_agg<<<ablk, 256, 0, stream>>>(h1, row, cnt, col, aggb, N);
    k_bucket_out<<<gblk, 256, 0, stream>>>(aggb, cnt, relW, relb, fuse, h0, Wout, bout, out, N);
}